// Round 2
// baseline (1219.922 us; speedup 1.0000x reference)
//
#include <hip/hip_runtime.h>

#define N_NODES 100000
#define N_EDGES 1600000
#define D_IN    256
#define D_HID   64
#define D_OUT   32
#define NPROP   10

#define SCAN_T 256
#define SCAN_E 8
#define SCAN_B (SCAN_T * SCAN_E)   // 2048 elements per scan block
#define NB1 ((N_NODES + SCAN_B - 1) / SCAN_B)  // 49

typedef _Float16 half_t;

__device__ inline unsigned int pk_h2(float a, float b) {
  union { half_t h[2]; unsigned int u; } q;
  q.h[0] = (half_t)a; q.h[1] = (half_t)b;
  return q.u;
}

// ---------------- MLP head: x0 = relu(F@W1 + b1) @ W2 + b2  -> fp16 ----------------
// 4 threads per node (j-split: 16 hidden units each) -> 400k threads,
// ~20 waves/CU (fixes the 17% occupancy / latency-bound round-1 profile).
// Layer-2 partials reduced across the 4 lanes via __shfl_xor; lane jg==0
// packs fp16 and stores 64B per node.
#define TPN 4
#define JP  (D_HID / TPN)   // 16

__global__ __launch_bounds__(256) void mlp_kernel(
    const float* __restrict__ F, const float* __restrict__ W1,
    const float* __restrict__ b1, const float* __restrict__ W2,
    const float* __restrict__ b2, half_t* __restrict__ x0h)
{
  int t = threadIdx.x;
  int g = t >> 2;            // node-local 0..63
  int jg = t & 3;            // j-group
  int n = blockIdx.x * 64 + g;
  int nc = n < N_NODES ? n : N_NODES - 1;
  const float4* frow = (const float4*)(F + (size_t)nc * D_IN);
  const int j0 = jg * JP;

  float h[JP];
#pragma unroll
  for (int j = 0; j < JP; ++j) h[j] = 0.f;

#pragma unroll 2
  for (int k4 = 0; k4 < D_IN / 4; ++k4) {
    float4 f4 = frow[k4];
    float fs[4] = {f4.x, f4.y, f4.z, f4.w};
#pragma unroll
    for (int u = 0; u < 4; ++u) {
      const float4* wr = (const float4*)(W1 + (size_t)(k4 * 4 + u) * D_HID + j0);
#pragma unroll
      for (int q = 0; q < JP / 4; ++q) {
        float4 w4 = wr[q];
        h[q * 4 + 0] = fmaf(fs[u], w4.x, h[q * 4 + 0]);
        h[q * 4 + 1] = fmaf(fs[u], w4.y, h[q * 4 + 1]);
        h[q * 4 + 2] = fmaf(fs[u], w4.z, h[q * 4 + 2]);
        h[q * 4 + 3] = fmaf(fs[u], w4.w, h[q * 4 + 3]);
      }
    }
  }

#pragma unroll
  for (int j = 0; j < JP; ++j) h[j] = fmaxf(h[j] + b1[j0 + j], 0.f);

  float p[D_OUT];
#pragma unroll
  for (int c = 0; c < D_OUT; ++c) p[c] = 0.f;

#pragma unroll 4
  for (int j = 0; j < JP; ++j) {
    const float4* wr = (const float4*)(W2 + (size_t)(j0 + j) * D_OUT);
    float hj = h[j];
#pragma unroll
    for (int q = 0; q < D_OUT / 4; ++q) {
      float4 w4 = wr[q];
      p[q * 4 + 0] = fmaf(hj, w4.x, p[q * 4 + 0]);
      p[q * 4 + 1] = fmaf(hj, w4.y, p[q * 4 + 1]);
      p[q * 4 + 2] = fmaf(hj, w4.z, p[q * 4 + 2]);
      p[q * 4 + 3] = fmaf(hj, w4.w, p[q * 4 + 3]);
    }
  }

  // reduce the 4 j-group partials (lanes 4k..4k+3 of the wave)
#pragma unroll
  for (int c = 0; c < D_OUT; ++c) {
    p[c] += __shfl_xor(p[c], 1);
    p[c] += __shfl_xor(p[c], 2);
  }

  if (jg == 0 && n < N_NODES) {
#pragma unroll
    for (int c = 0; c < D_OUT; ++c) p[c] += b2[c];   // uniform -> scalar loads
    int4* dst = (int4*)(x0h + (size_t)n * D_OUT);
#pragma unroll
    for (int q = 0; q < 4; ++q) {
      int4 v;
      v.x = (int)pk_h2(p[q * 8 + 0], p[q * 8 + 1]);
      v.y = (int)pk_h2(p[q * 8 + 2], p[q * 8 + 3]);
      v.z = (int)pk_h2(p[q * 8 + 4], p[q * 8 + 5]);
      v.w = (int)pk_h2(p[q * 8 + 6], p[q * 8 + 7]);
      dst[q] = v;
    }
  }
}

// ---------------- CSR build ----------------
__global__ __launch_bounds__(256) void hist_kernel(
    const int* __restrict__ row, int* __restrict__ counts)
{
  int e = blockIdx.x * 256 + threadIdx.x;
  if (e < N_EDGES) atomicAdd(&counts[row[e]], 1);
}

__global__ __launch_bounds__(256) void scan1_kernel(
    const int* __restrict__ cnt, int* __restrict__ part, int* __restrict__ bsum)
{
  __shared__ int lds[SCAN_T];
  int t = threadIdx.x;
  int base = blockIdx.x * SCAN_B + t * SCAN_E;
  int v[SCAN_E];
  int s = 0;
#pragma unroll
  for (int u = 0; u < SCAN_E; ++u) {
    int i = base + u;
    int x = (i < N_NODES) ? cnt[i] : 0;
    v[u] = s;
    s += x;
  }
  lds[t] = s;
  __syncthreads();
  for (int off = 1; off < SCAN_T; off <<= 1) {
    int add = (t >= off) ? lds[t - off] : 0;
    __syncthreads();
    lds[t] += add;
    __syncthreads();
  }
  int excl = lds[t] - s;
  if (t == SCAN_T - 1) bsum[blockIdx.x] = lds[SCAN_T - 1];
#pragma unroll
  for (int u = 0; u < SCAN_E; ++u) {
    int i = base + u;
    if (i < N_NODES) part[i] = excl + v[u];
  }
}

__global__ __launch_bounds__(256) void scan2_kernel(int* __restrict__ bsum, int nb)
{
  __shared__ int lds[SCAN_T];
  int t = threadIdx.x;
  int x = (t < nb) ? bsum[t] : 0;
  lds[t] = x;
  __syncthreads();
  for (int off = 1; off < SCAN_T; off <<= 1) {
    int add = (t >= off) ? lds[t - off] : 0;
    __syncthreads();
    lds[t] += add;
    __syncthreads();
  }
  if (t < nb) bsum[t] = lds[t] - x;
  if (t == nb - 1) bsum[nb] = lds[t];
}

__global__ __launch_bounds__(256) void scan3_kernel(
    int* __restrict__ part /*row_ptr*/, int* __restrict__ fill,
    const int* __restrict__ bsum, int nb)
{
  int t = threadIdx.x;
  int off = bsum[blockIdx.x];
  int base = blockIdx.x * SCAN_B + t * SCAN_E;
#pragma unroll
  for (int u = 0; u < SCAN_E; ++u) {
    int i = base + u;
    if (i < N_NODES) { int v = part[i] + off; part[i] = v; fill[i] = v; }
  }
  if (blockIdx.x == 0 && t == 0) part[N_NODES] = bsum[nb];
}

__global__ __launch_bounds__(256) void scatter_kernel(
    const int* __restrict__ row, const int* __restrict__ col,
    const float* __restrict__ vals, int* __restrict__ fill,
    int* __restrict__ col_s, float* __restrict__ val_s)
{
  int e = blockIdx.x * 256 + threadIdx.x;
  if (e < N_EDGES) {
    int r = row[e];
    int p = atomicAdd(&fill[r], 1);
    col_s[p] = col[e];
    val_s[p] = vals[e];
  }
}

// ---------------- propagation: xout = 0.9 * (A @ xin) + 0.1 * x0 ----------------
// 32 lanes per row, lane = channel. fp16 x: gather is 64B/edge (one cache
// line per edge), x footprint 6.4 MB (L2-friendly). fp32 accumulate.
// Final iteration writes fp32 straight to d_out.
__global__ __launch_bounds__(256) void spmm_kernel(
    const int* __restrict__ rp, const int* __restrict__ cs,
    const float* __restrict__ vs, const half_t* __restrict__ xin,
    const half_t* __restrict__ x0h, half_t* __restrict__ xout,
    float* __restrict__ fout, int last)
{
  int gt = blockIdx.x * 256 + threadIdx.x;
  int r = gt >> 5;
  int c = gt & 31;
  if (r >= N_NODES) return;
  int e0 = rp[r], e1 = rp[r + 1];
  float acc = 0.f;
  int e = e0;
  for (; e + 3 < e1; e += 4) {   // 4 gathers in flight
    int c0 = cs[e], c1 = cs[e + 1], c2 = cs[e + 2], c3 = cs[e + 3];
    float v0 = vs[e], v1 = vs[e + 1], v2 = vs[e + 2], v3 = vs[e + 3];
    float g0 = (float)xin[c0 * D_OUT + c];
    float g1 = (float)xin[c1 * D_OUT + c];
    float g2 = (float)xin[c2 * D_OUT + c];
    float g3 = (float)xin[c3 * D_OUT + c];
    acc = fmaf(v0, g0, acc);
    acc = fmaf(v1, g1, acc);
    acc = fmaf(v2, g2, acc);
    acc = fmaf(v3, g3, acc);
  }
  for (; e < e1; ++e)
    acc = fmaf(vs[e], (float)xin[cs[e] * D_OUT + c], acc);
  float res = 0.9f * acc + 0.1f * (float)x0h[r * D_OUT + c];
  if (last) fout[r * D_OUT + c] = res;
  else      xout[r * D_OUT + c] = (half_t)res;
}

extern "C" void kernel_launch(void* const* d_in, const int* in_sizes, int n_in,
                              void* d_out, int out_size, void* d_ws, size_t ws_size,
                              hipStream_t stream) {
  const float* F     = (const float*)d_in[0];
  const int*   row   = (const int*)  d_in[1];
  const int*   col   = (const int*)  d_in[2];
  const float* evals = (const float*)d_in[3];
  const float* W1    = (const float*)d_in[4];
  const float* b1    = (const float*)d_in[5];
  const float* W2    = (const float*)d_in[6];
  const float* b2    = (const float*)d_in[7];
  float* out = (float*)d_out;

  // workspace layout (256B-aligned offsets); total ~32.8 MB
  char* w = (char*)d_ws;
  half_t* x0h    = (half_t*)(w);                //  6,400,000 B
  half_t* P      = (half_t*)(w +  6400000);     //  6,400,000 B
  half_t* Q      = (half_t*)(w + 12800000);     //  6,400,000 B
  int*   row_ptr = (int*)   (w + 19200000);     //    400,128 B (N+1)
  int*   fill    = (int*)   (w + 19600128);     //    400,128 B
  int*   col_s   = (int*)   (w + 20000256);     //  6,400,000 B
  float* val_s   = (float*) (w + 26400256);     //  6,400,000 B
  int*   bsum    = (int*)   (w + 32800256);     //      4,096 B

  // 1) MLP head -> x0 (fp16)
  mlp_kernel<<<(N_NODES + 63) / 64, 256, 0, stream>>>(F, W1, b1, W2, b2, x0h);

  // 2) CSR build
  hipMemsetAsync(fill, 0, (size_t)N_NODES * 4, stream);
  hist_kernel<<<(N_EDGES + 255) / 256, 256, 0, stream>>>(row, fill);
  scan1_kernel<<<NB1, SCAN_T, 0, stream>>>(fill, row_ptr, bsum);
  scan2_kernel<<<1, SCAN_T, 0, stream>>>(bsum, NB1);
  scan3_kernel<<<NB1, SCAN_T, 0, stream>>>(row_ptr, fill, bsum, NB1);
  scatter_kernel<<<(N_EDGES + 255) / 256, 256, 0, stream>>>(row, col, evals,
                                                            fill, col_s, val_s);

  // 3) 10 propagation rounds: x0h -> P -> Q -> P ... final writes fp32 d_out
  const int grid_spmm = (N_NODES * 32 + 255) / 256;
  for (int i = 0; i < NPROP; ++i) {
    const half_t* xin = (i == 0) ? x0h : ((i & 1) ? P : Q);
    half_t* xout = (i & 1) ? Q : P;
    int last = (i == NPROP - 1);
    spmm_kernel<<<grid_spmm, 256, 0, stream>>>(
        row_ptr, col_s, val_s, xin, x0h, xout, out, last);
  }
}

// Round 3
// 696.049 us; speedup vs baseline: 1.7526x; 1.7526x over previous
//
#include <hip/hip_runtime.h>

#define N_NODES 100000
#define N_EDGES 1600000
#define D_IN    256
#define D_HID   64
#define D_OUT   32
#define NPROP   10

#define SCAN_T 256
#define SCAN_E 8
#define SCAN_B (SCAN_T * SCAN_E)
#define NB1 ((N_NODES + SCAN_B - 1) / SCAN_B)  // 49

typedef _Float16 half_t;
typedef _Float16 h8  __attribute__((ext_vector_type(8)));
typedef float    f4v __attribute__((ext_vector_type(4)));

// ---------------- weight pack: W1[256][64]->W1T[64][256] fp16, W2[64][32]->W2T[32][64] fp16
__global__ __launch_bounds__(256) void pack_kernel(
    const float* __restrict__ W1, const float* __restrict__ W2,
    half_t* __restrict__ W1T, half_t* __restrict__ W2T)
{
  int t = blockIdx.x * 256 + threadIdx.x;
  if (t < 64 * 256) { int n = t >> 8, k = t & 255; W1T[t] = (half_t)W1[k * 64 + n]; }
  if (t < 32 * 64)  { int n = t >> 6, k = t & 63;  W2T[t] = (half_t)W2[k * 32 + n]; }
}

// ---------------- MLP head via MFMA: x0 = relu(F@W1+b1)@W2+b2 -> fp16 ----------------
// Block = 256 thr = 4 waves = 16 nodes. Wave w computes hid cols [16w,16w+16).
// A-frag: lane holds F[node0+(lane&15)][k0+(lane>>4)*8 ..+8] (fp32 load, cvt fp16).
// B-frag: W1T[(hid0+(lane&15))*256 + k0+(lane>>4)*8] — contiguous 16B.
// C/D: col=lane&15, row=(lane>>4)*4+reg  [HW-verified mapping].
// Layer-2 routes h through LDS (stride 72 halves: 16B-aligned, 2-way-conflict only).
#define HSTRIDE 72

__global__ __launch_bounds__(256) void mlp_kernel(
    const float* __restrict__ F, const half_t* __restrict__ W1T,
    const float* __restrict__ b1, const half_t* __restrict__ W2T,
    const float* __restrict__ b2, half_t* __restrict__ x0h)
{
  __shared__ half_t h_lds[16 * HSTRIDE];
  __shared__ half_t out_lds[16 * 32];
  int t = threadIdx.x;
  int w = t >> 6, lane = t & 63;
  int m = lane & 15, q = lane >> 4;
  int node0 = blockIdx.x * 16;      // 6250 * 16 == 100000 exactly
  int hid0 = w * 16;

  // ---- layer 1: 8 x mfma_16x16x32 over K=256
  f4v acc = {0.f, 0.f, 0.f, 0.f};
  const float* arow = F + (size_t)(node0 + m) * D_IN + q * 8;
  const half_t* brow = W1T + (size_t)(hid0 + m) * D_IN + q * 8;
#pragma unroll
  for (int s = 0; s < 8; ++s) {
    float4 f0 = *(const float4*)(arow + s * 32);
    float4 f1 = *(const float4*)(arow + s * 32 + 4);
    h8 a;
    a[0] = (_Float16)f0.x; a[1] = (_Float16)f0.y;
    a[2] = (_Float16)f0.z; a[3] = (_Float16)f0.w;
    a[4] = (_Float16)f1.x; a[5] = (_Float16)f1.y;
    a[6] = (_Float16)f1.z; a[7] = (_Float16)f1.w;
    h8 b = *(const h8*)(brow + s * 32);
    acc = __builtin_amdgcn_mfma_f32_16x16x32_f16(a, b, acc, 0, 0, 0);
  }

  // ---- bias + relu -> h_lds (D layout: col=m (hid), rows q*4+i (node-local))
  {
    int col = hid0 + m;
    float bb = b1[col];
#pragma unroll
    for (int i = 0; i < 4; ++i) {
      float hv = fmaxf(acc[i] + bb, 0.f);
      h_lds[(q * 4 + i) * HSTRIDE + col] = (half_t)hv;
    }
  }
  __syncthreads();

  // ---- layer 2: waves 0,1 compute out cols [0,16) / [16,32), K=64 = 2 mfma
  if (w < 2) {
    f4v acc2 = {0.f, 0.f, 0.f, 0.f};
    int out0 = w * 16;
#pragma unroll
    for (int s = 0; s < 2; ++s) {
      h8 a = *(const h8*)(h_lds + m * HSTRIDE + s * 32 + q * 8);
      h8 b = *(const h8*)(W2T + (size_t)(out0 + m) * D_HID + s * 32 + q * 8);
      acc2 = __builtin_amdgcn_mfma_f32_16x16x32_f16(a, b, acc2, 0, 0, 0);
    }
    int oc = out0 + m;
    float b2v = b2[oc];
#pragma unroll
    for (int i = 0; i < 4; ++i)
      out_lds[(q * 4 + i) * 32 + oc] = (half_t)(acc2[i] + b2v);
  }
  __syncthreads();

  // ---- store 16 nodes x 32 ch (fp16) = 1 KB with 64 int4 stores
  if (t < 64) {
    int nl = t >> 2, qq = t & 3;
    *(int4*)(x0h + (size_t)(node0 + nl) * D_OUT + qq * 8) =
        *(const int4*)(out_lds + nl * 32 + qq * 8);
  }
}

// ---------------- CSR build ----------------
__global__ __launch_bounds__(256) void hist_kernel(
    const int* __restrict__ row, int* __restrict__ counts)
{
  int e = blockIdx.x * 256 + threadIdx.x;
  if (e < N_EDGES) atomicAdd(&counts[row[e]], 1);
}

__global__ __launch_bounds__(256) void scan1_kernel(
    const int* __restrict__ cnt, int* __restrict__ part, int* __restrict__ bsum)
{
  __shared__ int lds[SCAN_T];
  int t = threadIdx.x;
  int base = blockIdx.x * SCAN_B + t * SCAN_E;
  int v[SCAN_E];
  int s = 0;
#pragma unroll
  for (int u = 0; u < SCAN_E; ++u) {
    int i = base + u;
    int x = (i < N_NODES) ? cnt[i] : 0;
    v[u] = s;
    s += x;
  }
  lds[t] = s;
  __syncthreads();
  for (int off = 1; off < SCAN_T; off <<= 1) {
    int add = (t >= off) ? lds[t - off] : 0;
    __syncthreads();
    lds[t] += add;
    __syncthreads();
  }
  int excl = lds[t] - s;
  if (t == SCAN_T - 1) bsum[blockIdx.x] = lds[SCAN_T - 1];
#pragma unroll
  for (int u = 0; u < SCAN_E; ++u) {
    int i = base + u;
    if (i < N_NODES) part[i] = excl + v[u];
  }
}

__global__ __launch_bounds__(256) void scan2_kernel(int* __restrict__ bsum, int nb)
{
  __shared__ int lds[SCAN_T];
  int t = threadIdx.x;
  int x = (t < nb) ? bsum[t] : 0;
  lds[t] = x;
  __syncthreads();
  for (int off = 1; off < SCAN_T; off <<= 1) {
    int add = (t >= off) ? lds[t - off] : 0;
    __syncthreads();
    lds[t] += add;
    __syncthreads();
  }
  if (t < nb) bsum[t] = lds[t] - x;
  if (t == nb - 1) bsum[nb] = lds[t];
}

__global__ __launch_bounds__(256) void scan3_kernel(
    int* __restrict__ part /*row_ptr*/, int* __restrict__ fill,
    const int* __restrict__ bsum, int nb)
{
  int t = threadIdx.x;
  int off = bsum[blockIdx.x];
  int base = blockIdx.x * SCAN_B + t * SCAN_E;
#pragma unroll
  for (int u = 0; u < SCAN_E; ++u) {
    int i = base + u;
    if (i < N_NODES) { int v = part[i] + off; part[i] = v; fill[i] = v; }
  }
  if (blockIdx.x == 0 && t == 0) part[N_NODES] = bsum[nb];
}

// scatter (col,val) together as int2 -> one dwordx2 per edge in spmm
__global__ __launch_bounds__(256) void scatter_kernel(
    const int* __restrict__ row, const int* __restrict__ col,
    const float* __restrict__ vals, int* __restrict__ fill,
    int2* __restrict__ epack)
{
  int e = blockIdx.x * 256 + threadIdx.x;
  if (e < N_EDGES) {
    int r = row[e];
    int p = atomicAdd(&fill[r], 1);
    epack[p] = make_int2(col[e], __float_as_int(vals[e]));
  }
}

// ---------------- propagation: xout = 0.9*(A@xin) + 0.1*x0 ----------------
// 4 lanes per row, 8 fp16 channels per lane: gather = one dwordx4 (16B) per
// lane -> full 64B line per edge in 4 lane-slots (8x fewer VMEM instrs than
// the 2B/lane round-2 layout). (col,val) packed: one dwordx2 per edge.
__global__ __launch_bounds__(256) void spmm_kernel(
    const int* __restrict__ rp, const int2* __restrict__ ep,
    const half_t* __restrict__ xin, const half_t* __restrict__ x0h,
    half_t* __restrict__ xout, float* __restrict__ fout, int last)
{
  int gt = blockIdx.x * 256 + threadIdx.x;
  int r = gt >> 2;
  int c8 = (gt & 3) * 8;
  if (r >= N_NODES) return;
  int e0 = rp[r], e1 = rp[r + 1];

  float acc[8];
#pragma unroll
  for (int j = 0; j < 8; ++j) acc[j] = 0.f;

  int e = e0;
  for (; e + 1 < e1; e += 2) {
    int2 p0 = ep[e], p1 = ep[e + 1];
    float v0 = __int_as_float(p0.y);
    float v1 = __int_as_float(p1.y);
    h8 g0 = *(const h8*)(xin + (size_t)p0.x * D_OUT + c8);
    h8 g1 = *(const h8*)(xin + (size_t)p1.x * D_OUT + c8);
#pragma unroll
    for (int j = 0; j < 8; ++j) acc[j] = fmaf(v0, (float)g0[j], acc[j]);
#pragma unroll
    for (int j = 0; j < 8; ++j) acc[j] = fmaf(v1, (float)g1[j], acc[j]);
  }
  if (e < e1) {
    int2 p0 = ep[e];
    float v0 = __int_as_float(p0.y);
    h8 g0 = *(const h8*)(xin + (size_t)p0.x * D_OUT + c8);
#pragma unroll
    for (int j = 0; j < 8; ++j) acc[j] = fmaf(v0, (float)g0[j], acc[j]);
  }

  h8 x0v = *(const h8*)(x0h + (size_t)r * D_OUT + c8);
  if (last) {
    float4 o0, o1;
    o0.x = 0.9f * acc[0] + 0.1f * (float)x0v[0];
    o0.y = 0.9f * acc[1] + 0.1f * (float)x0v[1];
    o0.z = 0.9f * acc[2] + 0.1f * (float)x0v[2];
    o0.w = 0.9f * acc[3] + 0.1f * (float)x0v[3];
    o1.x = 0.9f * acc[4] + 0.1f * (float)x0v[4];
    o1.y = 0.9f * acc[5] + 0.1f * (float)x0v[5];
    o1.z = 0.9f * acc[6] + 0.1f * (float)x0v[6];
    o1.w = 0.9f * acc[7] + 0.1f * (float)x0v[7];
    float* dst = fout + (size_t)r * D_OUT + c8;
    ((float4*)dst)[0] = o0;
    ((float4*)dst)[1] = o1;
  } else {
    h8 o;
#pragma unroll
    for (int j = 0; j < 8; ++j)
      o[j] = (half_t)(0.9f * acc[j] + 0.1f * (float)x0v[j]);
    *(h8*)(xout + (size_t)r * D_OUT + c8) = o;
  }
}

extern "C" void kernel_launch(void* const* d_in, const int* in_sizes, int n_in,
                              void* d_out, int out_size, void* d_ws, size_t ws_size,
                              hipStream_t stream) {
  const float* F     = (const float*)d_in[0];
  const int*   row   = (const int*)  d_in[1];
  const int*   col   = (const int*)  d_in[2];
  const float* evals = (const float*)d_in[3];
  const float* W1    = (const float*)d_in[4];
  const float* b1    = (const float*)d_in[5];
  const float* W2    = (const float*)d_in[6];
  const float* b2    = (const float*)d_in[7];
  float* out = (float*)d_out;

  // workspace layout (128B-aligned offsets); total ~32.9 MB
  char* w = (char*)d_ws;
  half_t* x0h    = (half_t*)(w);                //  6,400,000 B
  half_t* P      = (half_t*)(w +  6400000);     //  6,400,000 B
  half_t* Q      = (half_t*)(w + 12800000);     //  6,400,000 B
  int2*  epack   = (int2*)  (w + 19200000);     // 12,800,000 B
  int*   row_ptr = (int*)   (w + 32000000);     //    400,128 B (N+1)
  int*   fill    = (int*)   (w + 32400128);     //    400,128 B
  int*   bsum    = (int*)   (w + 32800256);     //      4,096 B
  half_t* W1T    = (half_t*)(w + 32804352);     //     32,768 B
  half_t* W2T    = (half_t*)(w + 32837120);     //      4,096 B

  // 1) pack weights, then MFMA MLP head -> x0 (fp16)
  pack_kernel<<<64, 256, 0, stream>>>(W1, W2, W1T, W2T);
  mlp_kernel<<<N_NODES / 16, 256, 0, stream>>>(F, W1T, b1, W2T, b2, x0h);

  // 2) CSR build
  hipMemsetAsync(fill, 0, (size_t)N_NODES * 4, stream);
  hist_kernel<<<(N_EDGES + 255) / 256, 256, 0, stream>>>(row, fill);
  scan1_kernel<<<NB1, SCAN_T, 0, stream>>>(fill, row_ptr, bsum);
  scan2_kernel<<<1, SCAN_T, 0, stream>>>(bsum, NB1);
  scan3_kernel<<<NB1, SCAN_T, 0, stream>>>(row_ptr, fill, bsum, NB1);
  scatter_kernel<<<(N_EDGES + 255) / 256, 256, 0, stream>>>(row, col, evals,
                                                            fill, epack);

  // 3) 10 propagation rounds: x0h -> P -> Q -> P ... final writes fp32 d_out
  const int grid_spmm = (N_NODES * 4 + 255) / 256;
  for (int i = 0; i < NPROP; ++i) {
    const half_t* xin = (i == 0) ? x0h : ((i & 1) ? P : Q);
    half_t* xout = (i & 1) ? Q : P;
    int last = (i == NPROP - 1);
    spmm_kernel<<<grid_spmm, 256, 0, stream>>>(
        row_ptr, epack, xin, x0h, xout, out, last);
  }
}

// Round 4
// 668.973 us; speedup vs baseline: 1.8236x; 1.0405x over previous
//
#include <hip/hip_runtime.h>

#define N_NODES 100000
#define N_EDGES 1600000
#define D_IN    256
#define D_HID   64
#define D_OUT   32
#define NPROP   10

#define SCAN_T 256
#define SCAN_E 8
#define SCAN_B (SCAN_T * SCAN_E)
#define NB1 ((N_NODES + SCAN_B - 1) / SCAN_B)  // 49

typedef _Float16 half_t;
typedef _Float16 h8  __attribute__((ext_vector_type(8)));
typedef float    f4v __attribute__((ext_vector_type(4)));

// ---------------- weight pack: W1[256][64]->W1T[64][256] fp16, W2[64][32]->W2T[32][64] fp16
__global__ __launch_bounds__(256) void pack_kernel(
    const float* __restrict__ W1, const float* __restrict__ W2,
    half_t* __restrict__ W1T, half_t* __restrict__ W2T)
{
  int t = blockIdx.x * 256 + threadIdx.x;
  if (t < 64 * 256) { int n = t >> 8, k = t & 255; W1T[t] = (half_t)W1[k * 64 + n]; }
  if (t < 32 * 64)  { int n = t >> 6, k = t & 63;  W2T[t] = (half_t)W2[k * 32 + n]; }
}

// ---------------- MLP head via MFMA: x0 = relu(F@W1+b1)@W2+b2 -> fp16 ----------------
#define HSTRIDE 72

__global__ __launch_bounds__(256) void mlp_kernel(
    const float* __restrict__ F, const half_t* __restrict__ W1T,
    const float* __restrict__ b1, const half_t* __restrict__ W2T,
    const float* __restrict__ b2, half_t* __restrict__ x0h)
{
  __shared__ half_t h_lds[16 * HSTRIDE];
  __shared__ half_t out_lds[16 * 32];
  int t = threadIdx.x;
  int w = t >> 6, lane = t & 63;
  int m = lane & 15, q = lane >> 4;
  int node0 = blockIdx.x * 16;      // 6250 * 16 == 100000 exactly
  int hid0 = w * 16;

  // ---- layer 1: 8 x mfma_16x16x32 over K=256
  f4v acc = {0.f, 0.f, 0.f, 0.f};
  const float* arow = F + (size_t)(node0 + m) * D_IN + q * 8;
  const half_t* brow = W1T + (size_t)(hid0 + m) * D_IN + q * 8;
#pragma unroll
  for (int s = 0; s < 8; ++s) {
    float4 f0 = *(const float4*)(arow + s * 32);
    float4 f1 = *(const float4*)(arow + s * 32 + 4);
    h8 a;
    a[0] = (_Float16)f0.x; a[1] = (_Float16)f0.y;
    a[2] = (_Float16)f0.z; a[3] = (_Float16)f0.w;
    a[4] = (_Float16)f1.x; a[5] = (_Float16)f1.y;
    a[6] = (_Float16)f1.z; a[7] = (_Float16)f1.w;
    h8 b = *(const h8*)(brow + s * 32);
    acc = __builtin_amdgcn_mfma_f32_16x16x32_f16(a, b, acc, 0, 0, 0);
  }

  // ---- bias + relu -> h_lds (D layout: col=m (hid), rows q*4+i (node-local))
  {
    int col = hid0 + m;
    float bb = b1[col];
#pragma unroll
    for (int i = 0; i < 4; ++i) {
      float hv = fmaxf(acc[i] + bb, 0.f);
      h_lds[(q * 4 + i) * HSTRIDE + col] = (half_t)hv;
    }
  }
  __syncthreads();

  // ---- layer 2: waves 0,1 compute out cols [0,16) / [16,32), K=64 = 2 mfma
  if (w < 2) {
    f4v acc2 = {0.f, 0.f, 0.f, 0.f};
    int out0 = w * 16;
#pragma unroll
    for (int s = 0; s < 2; ++s) {
      h8 a = *(const h8*)(h_lds + m * HSTRIDE + s * 32 + q * 8);
      h8 b = *(const h8*)(W2T + (size_t)(out0 + m) * D_HID + s * 32 + q * 8);
      acc2 = __builtin_amdgcn_mfma_f32_16x16x32_f16(a, b, acc2, 0, 0, 0);
    }
    int oc = out0 + m;
    float b2v = b2[oc];
#pragma unroll
    for (int i = 0; i < 4; ++i)
      out_lds[(q * 4 + i) * 32 + oc] = (half_t)(acc2[i] + b2v);
  }
  __syncthreads();

  // ---- store 16 nodes x 32 ch (fp16) = 1 KB with 64 int4 stores
  if (t < 64) {
    int nl = t >> 2, qq = t & 3;
    *(int4*)(x0h + (size_t)(node0 + nl) * D_OUT + qq * 8) =
        *(const int4*)(out_lds + nl * 32 + qq * 8);
  }
}

// ---------------- CSR build ----------------
__global__ __launch_bounds__(256) void hist_kernel(
    const int* __restrict__ row, int* __restrict__ counts)
{
  int e = blockIdx.x * 256 + threadIdx.x;
  if (e < N_EDGES) atomicAdd(&counts[row[e]], 1);
}

__global__ __launch_bounds__(256) void scan1_kernel(
    const int* __restrict__ cnt, int* __restrict__ part, int* __restrict__ bsum)
{
  __shared__ int lds[SCAN_T];
  int t = threadIdx.x;
  int base = blockIdx.x * SCAN_B + t * SCAN_E;
  int v[SCAN_E];
  int s = 0;
#pragma unroll
  for (int u = 0; u < SCAN_E; ++u) {
    int i = base + u;
    int x = (i < N_NODES) ? cnt[i] : 0;
    v[u] = s;
    s += x;
  }
  lds[t] = s;
  __syncthreads();
  for (int off = 1; off < SCAN_T; off <<= 1) {
    int add = (t >= off) ? lds[t - off] : 0;
    __syncthreads();
    lds[t] += add;
    __syncthreads();
  }
  int excl = lds[t] - s;
  if (t == SCAN_T - 1) bsum[blockIdx.x] = lds[SCAN_T - 1];
#pragma unroll
  for (int u = 0; u < SCAN_E; ++u) {
    int i = base + u;
    if (i < N_NODES) part[i] = excl + v[u];
  }
}

__global__ __launch_bounds__(256) void scan2_kernel(int* __restrict__ bsum, int nb)
{
  __shared__ int lds[SCAN_T];
  int t = threadIdx.x;
  int x = (t < nb) ? bsum[t] : 0;
  lds[t] = x;
  __syncthreads();
  for (int off = 1; off < SCAN_T; off <<= 1) {
    int add = (t >= off) ? lds[t - off] : 0;
    __syncthreads();
    lds[t] += add;
    __syncthreads();
  }
  if (t < nb) bsum[t] = lds[t] - x;
  if (t == nb - 1) bsum[nb] = lds[t];
}

__global__ __launch_bounds__(256) void scan3_kernel(
    int* __restrict__ part /*row_ptr*/, int* __restrict__ fill,
    const int* __restrict__ bsum, int nb)
{
  int t = threadIdx.x;
  int off = bsum[blockIdx.x];
  int base = blockIdx.x * SCAN_B + t * SCAN_E;
#pragma unroll
  for (int u = 0; u < SCAN_E; ++u) {
    int i = base + u;
    if (i < N_NODES) { int v = part[i] + off; part[i] = v; fill[i] = v; }
  }
  if (blockIdx.x == 0 && t == 0) part[N_NODES] = bsum[nb];
}

// scatter (col,val) together as int2 -> one dwordx2 per edge in spmm
__global__ __launch_bounds__(256) void scatter_kernel(
    const int* __restrict__ row, const int* __restrict__ col,
    const float* __restrict__ vals, int* __restrict__ fill,
    int2* __restrict__ epack)
{
  int e = blockIdx.x * 256 + threadIdx.x;
  if (e < N_EDGES) {
    int r = row[e];
    int p = atomicAdd(&fill[r], 1);
    epack[p] = make_int2(col[e], __float_as_int(vals[e]));
  }
}

// ---------------- propagation: xout = 0.9*(A@xin) + 0.1*x0 ----------------
// 4 lanes per row, 8 fp16 channels per lane (dwordx4 gather = 64B line per
// edge across the 4 lanes). Unroll 4 with explicitly staged loads: 4 epack
// dwordx2 then 4 independent gathers in flight -> dependent-chain depth per
// row drops from deg/2 to deg/4 memory rounds (round-3 profile: latency-bound).
__global__ __launch_bounds__(256) void spmm_kernel(
    const int* __restrict__ rp, const int2* __restrict__ ep,
    const half_t* __restrict__ xin, const half_t* __restrict__ x0h,
    half_t* __restrict__ xout, float* __restrict__ fout, int last)
{
  int gt = blockIdx.x * 256 + threadIdx.x;
  int r = gt >> 2;
  int c8 = (gt & 3) * 8;
  if (r >= N_NODES) return;
  int e0 = rp[r], e1 = rp[r + 1];

  float acc[8];
#pragma unroll
  for (int j = 0; j < 8; ++j) acc[j] = 0.f;

  int e = e0;
  for (; e + 3 < e1; e += 4) {
    // stage 1: 4 independent (col,val) loads
    int2 p0 = ep[e];
    int2 p1 = ep[e + 1];
    int2 p2 = ep[e + 2];
    int2 p3 = ep[e + 3];
    // stage 2: 4 independent gathers
    h8 g0 = *(const h8*)(xin + (size_t)p0.x * D_OUT + c8);
    h8 g1 = *(const h8*)(xin + (size_t)p1.x * D_OUT + c8);
    h8 g2 = *(const h8*)(xin + (size_t)p2.x * D_OUT + c8);
    h8 g3 = *(const h8*)(xin + (size_t)p3.x * D_OUT + c8);
    float v0 = __int_as_float(p0.y);
    float v1 = __int_as_float(p1.y);
    float v2 = __int_as_float(p2.y);
    float v3 = __int_as_float(p3.y);
#pragma unroll
    for (int j = 0; j < 8; ++j) {
      acc[j] = fmaf(v0, (float)g0[j], acc[j]);
      acc[j] = fmaf(v1, (float)g1[j], acc[j]);
      acc[j] = fmaf(v2, (float)g2[j], acc[j]);
      acc[j] = fmaf(v3, (float)g3[j], acc[j]);
    }
  }
  for (; e < e1; ++e) {
    int2 p0 = ep[e];
    float v0 = __int_as_float(p0.y);
    h8 g0 = *(const h8*)(xin + (size_t)p0.x * D_OUT + c8);
#pragma unroll
    for (int j = 0; j < 8; ++j) acc[j] = fmaf(v0, (float)g0[j], acc[j]);
  }

  h8 x0v = *(const h8*)(x0h + (size_t)r * D_OUT + c8);
  if (last) {
    float4 o0, o1;
    o0.x = 0.9f * acc[0] + 0.1f * (float)x0v[0];
    o0.y = 0.9f * acc[1] + 0.1f * (float)x0v[1];
    o0.z = 0.9f * acc[2] + 0.1f * (float)x0v[2];
    o0.w = 0.9f * acc[3] + 0.1f * (float)x0v[3];
    o1.x = 0.9f * acc[4] + 0.1f * (float)x0v[4];
    o1.y = 0.9f * acc[5] + 0.1f * (float)x0v[5];
    o1.z = 0.9f * acc[6] + 0.1f * (float)x0v[6];
    o1.w = 0.9f * acc[7] + 0.1f * (float)x0v[7];
    float* dst = fout + (size_t)r * D_OUT + c8;
    ((float4*)dst)[0] = o0;
    ((float4*)dst)[1] = o1;
  } else {
    h8 o;
#pragma unroll
    for (int j = 0; j < 8; ++j)
      o[j] = (half_t)(0.9f * acc[j] + 0.1f * (float)x0v[j]);
    *(h8*)(xout + (size_t)r * D_OUT + c8) = o;
  }
}

extern "C" void kernel_launch(void* const* d_in, const int* in_sizes, int n_in,
                              void* d_out, int out_size, void* d_ws, size_t ws_size,
                              hipStream_t stream) {
  const float* F     = (const float*)d_in[0];
  const int*   row   = (const int*)  d_in[1];
  const int*   col   = (const int*)  d_in[2];
  const float* evals = (const float*)d_in[3];
  const float* W1    = (const float*)d_in[4];
  const float* b1    = (const float*)d_in[5];
  const float* W2    = (const float*)d_in[6];
  const float* b2    = (const float*)d_in[7];
  float* out = (float*)d_out;

  // workspace layout (128B-aligned offsets); total ~32.9 MB
  char* w = (char*)d_ws;
  half_t* x0h    = (half_t*)(w);                //  6,400,000 B
  half_t* P      = (half_t*)(w +  6400000);     //  6,400,000 B
  half_t* Q      = (half_t*)(w + 12800000);     //  6,400,000 B
  int2*  epack   = (int2*)  (w + 19200000);     // 12,800,000 B
  int*   row_ptr = (int*)   (w + 32000000);     //    400,128 B (N+1)
  int*   fill    = (int*)   (w + 32400128);     //    400,128 B
  int*   bsum    = (int*)   (w + 32800256);     //      4,096 B
  half_t* W1T    = (half_t*)(w + 32804352);     //     32,768 B
  half_t* W2T    = (half_t*)(w + 32837120);     //      4,096 B

  // 1) pack weights, then MFMA MLP head -> x0 (fp16)
  pack_kernel<<<64, 256, 0, stream>>>(W1, W2, W1T, W2T);
  mlp_kernel<<<N_NODES / 16, 256, 0, stream>>>(F, W1T, b1, W2T, b2, x0h);

  // 2) CSR build
  hipMemsetAsync(fill, 0, (size_t)N_NODES * 4, stream);
  hist_kernel<<<(N_EDGES + 255) / 256, 256, 0, stream>>>(row, fill);
  scan1_kernel<<<NB1, SCAN_T, 0, stream>>>(fill, row_ptr, bsum);
  scan2_kernel<<<1, SCAN_T, 0, stream>>>(bsum, NB1);
  scan3_kernel<<<NB1, SCAN_T, 0, stream>>>(row_ptr, fill, bsum, NB1);
  scatter_kernel<<<(N_EDGES + 255) / 256, 256, 0, stream>>>(row, col, evals,
                                                            fill, epack);

  // 3) 10 propagation rounds: x0h -> P -> Q -> P ... final writes fp32 d_out
  const int grid_spmm = (N_NODES * 4 + 255) / 256;
  for (int i = 0; i < NPROP; ++i) {
    const half_t* xin = (i == 0) ? x0h : ((i & 1) ? P : Q);
    half_t* xout = (i & 1) ? Q : P;
    int last = (i == NPROP - 1);
    spmm_kernel<<<grid_spmm, 256, 0, stream>>>(
        row_ptr, epack, xin, x0h, xout, out, last);
  }
}

// Round 5
// 557.779 us; speedup vs baseline: 2.1871x; 1.1994x over previous
//
#include <hip/hip_runtime.h>

#define N_NODES 100000
#define N_EDGES 1600000
#define D_IN    256
#define D_HID   64
#define D_OUT   32
#define NPROP   10

#define NBUCK 196          // bucket = row >> 9 (512 rows/bucket)
#define CHUNK 6080         // edges per bscatter block (LDS-limited)
#define NCHUNK ((N_EDGES + CHUNK - 1) / CHUNK)   // 264

typedef _Float16 half_t;
typedef _Float16 h8  __attribute__((ext_vector_type(8)));
typedef _Float16 h4  __attribute__((ext_vector_type(4)));
typedef float    f4v __attribute__((ext_vector_type(4)));

// ---------------- weight pack ----------------
__global__ __launch_bounds__(256) void pack_kernel(
    const float* __restrict__ W1, const float* __restrict__ W2,
    half_t* __restrict__ W1T, half_t* __restrict__ W2T)
{
  int t = blockIdx.x * 256 + threadIdx.x;
  if (t < 64 * 256) { int n = t >> 8, k = t & 255; W1T[t] = (half_t)W1[k * 64 + n]; }
  if (t < 32 * 64)  { int n = t >> 6, k = t & 63;  W2T[t] = (half_t)W2[k * 32 + n]; }
}

// ---------------- MLP head via MFMA (known-good from round 3) ----------------
#define HSTRIDE 72

__global__ __launch_bounds__(256) void mlp_kernel(
    const float* __restrict__ F, const half_t* __restrict__ W1T,
    const float* __restrict__ b1, const half_t* __restrict__ W2T,
    const float* __restrict__ b2, half_t* __restrict__ x0h)
{
  __shared__ half_t h_lds[16 * HSTRIDE];
  __shared__ half_t out_lds[16 * 32];
  int t = threadIdx.x;
  int w = t >> 6, lane = t & 63;
  int m = lane & 15, q = lane >> 4;
  int node0 = blockIdx.x * 16;
  int hid0 = w * 16;

  f4v acc = {0.f, 0.f, 0.f, 0.f};
  const float* arow = F + (size_t)(node0 + m) * D_IN + q * 8;
  const half_t* brow = W1T + (size_t)(hid0 + m) * D_IN + q * 8;
#pragma unroll
  for (int s = 0; s < 8; ++s) {
    float4 f0 = *(const float4*)(arow + s * 32);
    float4 f1 = *(const float4*)(arow + s * 32 + 4);
    h8 a;
    a[0] = (_Float16)f0.x; a[1] = (_Float16)f0.y;
    a[2] = (_Float16)f0.z; a[3] = (_Float16)f0.w;
    a[4] = (_Float16)f1.x; a[5] = (_Float16)f1.y;
    a[6] = (_Float16)f1.z; a[7] = (_Float16)f1.w;
    h8 b = *(const h8*)(brow + s * 32);
    acc = __builtin_amdgcn_mfma_f32_16x16x32_f16(a, b, acc, 0, 0, 0);
  }

  {
    int col = hid0 + m;
    float bb = b1[col];
#pragma unroll
    for (int i = 0; i < 4; ++i) {
      float hv = fmaxf(acc[i] + bb, 0.f);
      h_lds[(q * 4 + i) * HSTRIDE + col] = (half_t)hv;
    }
  }
  __syncthreads();

  if (w < 2) {
    f4v acc2 = {0.f, 0.f, 0.f, 0.f};
    int out0 = w * 16;
#pragma unroll
    for (int s = 0; s < 2; ++s) {
      h8 a = *(const h8*)(h_lds + m * HSTRIDE + s * 32 + q * 8);
      h8 b = *(const h8*)(W2T + (size_t)(out0 + m) * D_HID + s * 32 + q * 8);
      acc2 = __builtin_amdgcn_mfma_f32_16x16x32_f16(a, b, acc2, 0, 0, 0);
    }
    int oc = out0 + m;
    float b2v = b2[oc];
#pragma unroll
    for (int i = 0; i < 4; ++i)
      out_lds[(q * 4 + i) * 32 + oc] = (half_t)(acc2[i] + b2v);
  }
  __syncthreads();

  if (t < 64) {
    int nl = t >> 2, qq = t & 3;
    *(int4*)(x0h + (size_t)(node0 + nl) * D_OUT + qq * 8) =
        *(const int4*)(out_lds + nl * 32 + qq * 8);
  }
}

// ---------------- CSR build, two-pass bucketed sort ----------------
// K1: bucket histogram (LDS-aggregated -> few global atomics)
__global__ __launch_bounds__(256) void bhist_kernel(
    const int* __restrict__ row, int* __restrict__ bcnt)
{
  __shared__ int lb[NBUCK];
  int t = threadIdx.x;
  for (int i = t; i < NBUCK; i += 256) lb[i] = 0;
  __syncthreads();
  int stride = gridDim.x * 256;
  for (int e = blockIdx.x * 256 + t; e < N_EDGES; e += stride)
    atomicAdd(&lb[row[e] >> 9], 1);
  __syncthreads();
  for (int i = t; i < NBUCK; i += 256)
    if (lb[i]) atomicAdd(&bcnt[i], lb[i]);
}

// K3: dual exclusive scan over NBUCK values: bbase (raw), pbase (padded reserve).
// reserve_b = align4(bcnt_b) + 3*512  (worst-case per-row pad; slack is
// redistributed exactly in bsort so the layout stays hole-free).
__global__ __launch_bounds__(256) void bscan_kernel(
    const int* __restrict__ bcnt, int* __restrict__ bbase, int* __restrict__ pbase)
{
  __shared__ int l1[256], l2[256];
  int t = threadIdx.x;
  int a = (t < NBUCK) ? bcnt[t] : 0;
  int r = (t < NBUCK) ? (((a + 3) & ~3) + 3 * 512) : 0;
  l1[t] = a; l2[t] = r;
  __syncthreads();
  for (int off = 1; off < 256; off <<= 1) {
    int x1 = (t >= off) ? l1[t - off] : 0;
    int x2 = (t >= off) ? l2[t - off] : 0;
    __syncthreads();
    l1[t] += x1; l2[t] += x2;
    __syncthreads();
  }
  if (t < NBUCK) { bbase[t] = l1[t] - a; pbase[t] = l2[t] - r; }
  if (t == NBUCK - 1) { bbase[NBUCK] = l1[t]; pbase[NBUCK] = l2[t]; }
}

// K4: LDS-binned bucket scatter. Each block bins CHUNK edges by bucket in LDS,
// reserves per-bucket ranges with one atomic each, then writes runs coalesced.
// Payload packed: (col | local_row<<17, val_bits).
__global__ __launch_bounds__(256) void bscatter_kernel(
    const int* __restrict__ row, const int* __restrict__ col,
    const float* __restrict__ vals, int* __restrict__ bfill,
    const int* __restrict__ bbase, int2* __restrict__ ebuck)
{
  __shared__ int2 img[CHUNK];                 // 48,640 B
  __shared__ unsigned short sbk[CHUNK];       // 12,160 B
  __shared__ int cnt[NBUCK], base[NBUCK], gb[NBUCK], fil[NBUCK];
  __shared__ int ssc[256];
  int t = threadIdx.x;
  int e0 = blockIdx.x * CHUNK;
  int n = min(CHUNK, N_EDGES - e0);

  for (int i = t; i < NBUCK; i += 256) { cnt[i] = 0; fil[i] = 0; }
  __syncthreads();
  // phase 1: local bucket counts
  for (int i = t; i < n; i += 256) atomicAdd(&cnt[row[e0 + i] >> 9], 1);
  __syncthreads();
  // phase 2: scan counts -> local base; reserve global ranges
  int c = (t < NBUCK) ? cnt[t] : 0;
  ssc[t] = c;
  __syncthreads();
  for (int off = 1; off < 256; off <<= 1) {
    int add = (t >= off) ? ssc[t - off] : 0;
    __syncthreads();
    ssc[t] += add;
    __syncthreads();
  }
  if (t < NBUCK) {
    base[t] = ssc[t] - c;
    gb[t] = c ? atomicAdd(&bfill[t], c) : 0;
  }
  __syncthreads();
  // phase 3: place edges into LDS image grouped by bucket
  for (int i = t; i < n; i += 256) {
    int r = row[e0 + i];
    int bk = r >> 9;
    int p = base[bk] + atomicAdd(&fil[bk], 1);
    img[p] = make_int2(col[e0 + i] | ((r & 511) << 17),
                       __float_as_int(vals[e0 + i]));
    sbk[p] = (unsigned short)bk;
  }
  __syncthreads();
  // phase 4: coalesced burst copy of runs to global
  for (int i = t; i < n; i += 256) {
    int bk = sbk[i];
    ebuck[bbase[bk] + gb[bk] + (i - base[bk])] = img[i];
  }
}

// K5: per-bucket exact sort + pad. Block b owns rows [512b, 512b+nr):
// LDS row histogram (no global atomics), padded scan (each row padded to
// multiple of 4; reserve slack spread +4 over first `units` rows), emits
// row_ptr, scatters into its private ~64KB epack region (XCD-L2 absorbed),
// then fills pad slots with zero-weight edges.
__global__ __launch_bounds__(256) void bsort_kernel(
    const int* __restrict__ bbase, const int* __restrict__ pbase,
    const int2* __restrict__ ebuck, int2* __restrict__ epack,
    int* __restrict__ row_ptr)
{
  __shared__ int acnt[512], loff[513], lfill[512], ssc[256];
  int b = blockIdx.x, t = threadIdx.x;
  int r0 = b * 512;
  int nr = min(512, N_NODES - r0);
  int eb = bbase[b];
  int ne = bbase[b + 1] - eb;
  int pb = pbase[b];

  acnt[t] = 0; acnt[t + 256] = 0;
  lfill[t] = 0; lfill[t + 256] = 0;
  __syncthreads();
  // phase A: local row histogram
  for (int i = t; i < ne; i += 256)
    atomicAdd(&acnt[((unsigned)ebuck[eb + i].x) >> 17], 1);
  __syncthreads();
  // phase B: padded scan (2 rows per thread)
  int i0 = 2 * t, i1 = 2 * t + 1;
  int a0 = acnt[i0], a1 = acnt[i1];
  int p0 = (a0 + 3) & ~3, p1 = (a1 + 3) & ~3;
  int s = p0 + p1;
  ssc[t] = s;
  __syncthreads();
  for (int off = 1; off < 256; off <<= 1) {
    int add = (t >= off) ? ssc[t - off] : 0;
    __syncthreads();
    ssc[t] += add;
    __syncthreads();
  }
  int ex = ssc[t] - s;
  loff[i0] = ex;
  loff[i1] = ex + p0;
  if (t == 255) loff[512] = ssc[255];
  __syncthreads();
  int T = ssc[255];
  int slack = (pbase[b + 1] - pb) - T;       // multiple of 4, >= 0
  int units = min(slack >> 2, nr);
  // row_ptr (+4*min(i,units) shift folds the slack in, keeping layout hole-free)
  if (i0 < nr) row_ptr[r0 + i0] = pb + loff[i0] + 4 * min(i0, units);
  if (i1 < nr) row_ptr[r0 + i1] = pb + loff[i1] + 4 * min(i1, units);
  if (b == NBUCK - 1 && t == 0)
    row_ptr[N_NODES] = pb + loff[nr] + 4 * units;
  __syncthreads();
  // phase C: scatter into private region (random within ~64KB -> L2-absorbed)
  for (int i = t; i < ne; i += 256) {
    int2 ed = ebuck[eb + i];
    int lr = ((unsigned)ed.x) >> 17;
    int cl = ed.x & 0x1FFFF;
    int p = loff[lr] + 4 * min(lr, units) + atomicAdd(&lfill[lr], 1);
    epack[pb + p] = make_int2(cl, ed.y);
  }
  __syncthreads();
  // phase D: zero-weight pad edges (col=0, val=0)
  for (int i = t; i < nr; i += 256) {
    int a = acnt[i];
    int size_i = ((a + 3) & ~3) + 4 * (i < units);
    int st = loff[i] + 4 * min(i, units);
    for (int p = st + a; p < st + size_i; ++p)
      epack[pb + p] = make_int2(0, 0);
  }
}

// ---------------- propagation: xout = 0.9*(A@xin) + 0.1*x0 ----------------
// 8 lanes per row, 4 fp16 channels per lane (dwordx2 gather; 8 lanes cover the
// row's 64B line). Grid = 12500 waves -> full 32-waves/CU occupancy (round-4
// profile: MLP-limited at 24 waves/CU). Degrees padded to multiples of 4 ->
// no remainder loop; pad edges are (col=0, val=0).
__global__ __launch_bounds__(256) void spmm_kernel(
    const int* __restrict__ rp, const int2* __restrict__ ep,
    const half_t* __restrict__ xin, const half_t* __restrict__ x0h,
    half_t* __restrict__ xout, float* __restrict__ fout, int last)
{
  int gt = blockIdx.x * 256 + threadIdx.x;
  int r = gt >> 3;
  int c4 = (gt & 7) * 4;
  if (r >= N_NODES) return;
  int e0 = rp[r], e1 = rp[r + 1];

  float acc[4] = {0.f, 0.f, 0.f, 0.f};
  for (int e = e0; e < e1; e += 4) {
    int2 p0 = ep[e];
    int2 p1 = ep[e + 1];
    int2 p2 = ep[e + 2];
    int2 p3 = ep[e + 3];
    h4 g0 = *(const h4*)(xin + (size_t)p0.x * D_OUT + c4);
    h4 g1 = *(const h4*)(xin + (size_t)p1.x * D_OUT + c4);
    h4 g2 = *(const h4*)(xin + (size_t)p2.x * D_OUT + c4);
    h4 g3 = *(const h4*)(xin + (size_t)p3.x * D_OUT + c4);
    float v0 = __int_as_float(p0.y);
    float v1 = __int_as_float(p1.y);
    float v2 = __int_as_float(p2.y);
    float v3 = __int_as_float(p3.y);
#pragma unroll
    for (int j = 0; j < 4; ++j) {
      acc[j] = fmaf(v0, (float)g0[j], acc[j]);
      acc[j] = fmaf(v1, (float)g1[j], acc[j]);
      acc[j] = fmaf(v2, (float)g2[j], acc[j]);
      acc[j] = fmaf(v3, (float)g3[j], acc[j]);
    }
  }

  h4 x0v = *(const h4*)(x0h + (size_t)r * D_OUT + c4);
  if (last) {
    float4 o;
    o.x = 0.9f * acc[0] + 0.1f * (float)x0v[0];
    o.y = 0.9f * acc[1] + 0.1f * (float)x0v[1];
    o.z = 0.9f * acc[2] + 0.1f * (float)x0v[2];
    o.w = 0.9f * acc[3] + 0.1f * (float)x0v[3];
    *(float4*)(fout + (size_t)r * D_OUT + c4) = o;
  } else {
    h4 o;
#pragma unroll
    for (int j = 0; j < 4; ++j)
      o[j] = (half_t)(0.9f * acc[j] + 0.1f * (float)x0v[j]);
    *(h4*)(xout + (size_t)r * D_OUT + c4) = o;
  }
}

extern "C" void kernel_launch(void* const* d_in, const int* in_sizes, int n_in,
                              void* d_out, int out_size, void* d_ws, size_t ws_size,
                              hipStream_t stream) {
  const float* F     = (const float*)d_in[0];
  const int*   row   = (const int*)  d_in[1];
  const int*   col   = (const int*)  d_in[2];
  const float* evals = (const float*)d_in[3];
  const float* W1    = (const float*)d_in[4];
  const float* b1    = (const float*)d_in[5];
  const float* W2    = (const float*)d_in[6];
  const float* b2    = (const float*)d_in[7];
  float* out = (float*)d_out;

  // workspace layout (~35.1 MB). ebuck aliases P+Q: ebuck is dead before the
  // first spmm writes P (stream-ordered).
  char* w = (char*)d_ws;
  half_t* x0h    = (half_t*)(w);                //  6,400,000
  half_t* P      = (half_t*)(w +  6400000);     //  6,400,000 (alias ebuck lo)
  half_t* Q      = (half_t*)(w + 12800000);     //  6,400,000 (alias ebuck hi)
  int2*   ebuck  = (int2*)  (w +  6400000);     // 12,800,000
  int2*   epack  = (int2*)  (w + 19200000);     // 15,400,000 (padded CSR)
  int*   row_ptr = (int*)   (w + 34600192);     //    400,128 (N+1)
  int*   bcnt    = (int*)   (w + 35000576);     //      1,024 (zeroed)
  int*   bfill   = (int*)   (w + 35001600);     //      1,024 (zeroed)
  int*   bbase   = (int*)   (w + 35002624);     //      1,024
  int*   pbase   = (int*)   (w + 35003648);     //      1,024
  half_t* W1T    = (half_t*)(w + 35004672);     //     32,768
  half_t* W2T    = (half_t*)(w + 35037440);     //      4,096

  // 1) MLP head -> x0 (fp16)
  pack_kernel<<<64, 256, 0, stream>>>(W1, W2, W1T, W2T);
  mlp_kernel<<<N_NODES / 16, 256, 0, stream>>>(F, W1T, b1, W2T, b2, x0h);

  // 2) CSR build (bucketed two-pass sort, padded rows)
  hipMemsetAsync(bcnt, 0, 2048, stream);   // bcnt + bfill
  bhist_kernel<<<640, 256, 0, stream>>>(row, bcnt);
  bscan_kernel<<<1, 256, 0, stream>>>(bcnt, bbase, pbase);
  bscatter_kernel<<<NCHUNK, 256, 0, stream>>>(row, col, evals, bfill, bbase, ebuck);
  bsort_kernel<<<NBUCK, 256, 0, stream>>>(bbase, pbase, ebuck, epack, row_ptr);

  // 3) 10 propagation rounds: x0h -> P -> Q -> ... final writes fp32 d_out
  const int grid_spmm = (N_NODES * 8 + 255) / 256;
  for (int i = 0; i < NPROP; ++i) {
    const half_t* xin = (i == 0) ? x0h : ((i & 1) ? P : Q);
    half_t* xout = (i & 1) ? Q : P;
    int last = (i == NPROP - 1);
    spmm_kernel<<<grid_spmm, 256, 0, stream>>>(
        row_ptr, epack, xin, x0h, xout, out, last);
  }
}